// Round 7
// baseline (527.015 us; speedup 1.0000x reference)
//
#include <hip/hip_runtime.h>

// ---------------- bf16 pack/unpack (RNE) ----------------

__device__ inline unsigned pack_bf16(float a, float b) {
  unsigned ua = __float_as_uint(a), ub = __float_as_uint(b);
  ua += 0x7fffu + ((ua >> 16) & 1u);
  ub += 0x7fffu + ((ub >> 16) & 1u);
  return (ua >> 16) | (ub & 0xffff0000u);
}
__device__ inline float unpack_lo(unsigned u) { return __uint_as_float(u << 16); }
__device__ inline float unpack_hi(unsigned u) { return __uint_as_float(u & 0xffff0000u); }

// ---------------- CSR build ----------------
// NOTE: harness delivers integer inputs as int32 (reference int64 is narrowed).

__global__ void k_count(const int* __restrict__ dst, int E, int* __restrict__ deg) {
  int i = blockIdx.x * blockDim.x + threadIdx.x;
  int stride = gridDim.x * blockDim.x;
  for (; i < E; i += stride) {
    atomicAdd(&deg[dst[i]], 1);
  }
}

// Per-wave prefix sum + one global-cursor atomic per wave allocates each
// node's CSR slice. fillcur is initialized to row_start so the scatter needs
// only ONE random access (atomic) instead of load+atomic (R6: 3 random line
// touches/edge -> 2).
__global__ void k_alloc(const int* __restrict__ deg, int N, float* __restrict__ dinv,
                        int* __restrict__ row_start, int* __restrict__ fillcur,
                        int* __restrict__ cursor) {
  int i = blockIdx.x * blockDim.x + threadIdx.x;
  int lane = threadIdx.x & 63;
  int cnt = (i < N) ? deg[i] : 0;
  int v = cnt;
#pragma unroll
  for (int off = 1; off < 64; off <<= 1) {
    int u = __shfl_up(v, off);
    if (lane >= off) v += u;
  }
  int total = __shfl(v, 63);
  int base = 0;
  if (lane == 0) base = atomicAdd(cursor, total);
  base = __shfl(base, 0);
  if (i < N) {
    int rs = base + v - cnt;                 // exclusive prefix within wave
    row_start[i] = rs;
    fillcur[i] = rs;
    dinv[i] = rsqrtf((float)(cnt + 1));      // +1 for the self-loop
  }
}

__global__ void k_scatter(const int* __restrict__ src, const int* __restrict__ dst,
                          int E, int* __restrict__ fillcur, int* __restrict__ col) {
  int i = blockIdx.x * blockDim.x + threadIdx.x;
  if (i >= E) return;
  int s = src[i], d = dst[i];
  int p = atomicAdd(&fillcur[d], 1);
  __builtin_nontemporal_store(s, &col[p]);
}

// ---------------- Tiled GEMM: G[r,c] = bf16(dinv[r] * sum_k X[r,k] * W[k,c]) ----------------
// Block 256. Thread = (cx, ry). Output packed bf16 (gather payload; fp32 acc).
// History: R3/R4 VGPR=256 + ~500MB scratch spill from unbounded k4 unroll;
// fixed by unroll 2 + launch_bounds(256,4) (128-VGPR cap). Xl pad +4 floats
// keeps b128 LDS reads conflict-free (R4: conflicts 3.2M -> 0).

template <int CT, int RPT, int NC, int KP>
__global__ __launch_bounds__(256, 4) void k_gemm_t(const float* __restrict__ X,
                                                   const float* __restrict__ W,
                                                   const float* __restrict__ dinv,
                                                   unsigned* __restrict__ G,  // packed bf16, NC/2 uints per row
                                                   int N) {
  constexpr int K = 128;
  constexpr int LDX = K + 4;
  constexpr int RT = 256 / CT;
  constexpr int RB = RT * RPT;
  constexpr int PHASES = K / KP;
  constexpr int KV = K / 4;

  __shared__ float Wl[KP * NC];
  __shared__ float Xl[RB * LDX];

  const int tid = threadIdx.x;
  const int row0 = blockIdx.x * RB;

  const float4* X4 = (const float4*)(X + (size_t)row0 * K);
  if (row0 + RB <= N) {
#pragma unroll
    for (int i = tid; i < RB * KV; i += 256) {
      int r = i / KV, c = i % KV;
      *(float4*)&Xl[r * LDX + c * 4] = X4[i];
    }
  } else {
    int lim = (N - row0) * KV;
    for (int i = tid; i < RB * KV; i += 256) {
      int r = i / KV, c = i % KV;
      *(float4*)&Xl[r * LDX + c * 4] =
          (i < lim) ? X4[i] : float4{0.f, 0.f, 0.f, 0.f};
    }
  }

  const int cx = tid % CT;
  const int ry = tid / CT;
  const int c0 = cx * 4;
  const bool cact = (c0 < NC);
  const int c0c = cact ? c0 : 0;

  float acc[RPT][4];
#pragma unroll
  for (int j = 0; j < RPT; ++j)
#pragma unroll
    for (int c = 0; c < 4; ++c) acc[j][c] = 0.f;

  for (int p = 0; p < PHASES; ++p) {
    constexpr int WV = KP * NC / 4;
    const float4* W4 = (const float4*)(W + (size_t)p * KP * NC);
    float4* Wl4 = (float4*)Wl;
    if (p > 0) __syncthreads();
#pragma unroll
    for (int i = tid; i < WV; i += 256) Wl4[i] = W4[i];
    __syncthreads();

#pragma unroll 2
    for (int k4 = 0; k4 < KP / 4; ++k4) {
      float4 xv[RPT], wv[4];
#pragma unroll
      for (int j = 0; j < RPT; ++j)
        xv[j] = *(const float4*)&Xl[(ry * RPT + j) * LDX + p * KP + k4 * 4];
#pragma unroll
      for (int kk = 0; kk < 4; ++kk)
        wv[kk] = *(const float4*)&Wl[(k4 * 4 + kk) * NC + c0c];
#pragma unroll
      for (int kk = 0; kk < 4; ++kk)
#pragma unroll
        for (int j = 0; j < RPT; ++j) {
          float xs = ((const float*)&xv[j])[kk];
#pragma unroll
          for (int c = 0; c < 4; ++c)
            acc[j][c] = fmaf(xs, ((const float*)&wv[kk])[c], acc[j][c]);
        }
    }
  }

  if (cact) {
#pragma unroll
    for (int j = 0; j < RPT; ++j) {
      int r = row0 + ry * RPT + j;
      if (r < N) {
        float d = dinv[r];
        uint2 o;
        o.x = pack_bf16(acc[j][0] * d, acc[j][1] * d);
        o.y = pack_bf16(acc[j][2] * d, acc[j][3] * d);
        *(uint2*)&G[(size_t)r * (NC / 2) + c0 / 2] = o;
      }
    }
  }
}

// ---------------- Aggregation 1: h2 = relu(dinv[n]*(g1[n] + sum g1[nbr]) + b1) ----------------
// g1 packed bf16: 64 uints (128 feats) per row = 256 B. One wave per node,
// one uint per lane; fp32 accumulate; unroll 8 for gather ILP (R6 evidence:
// halving payload bytes barely moved total -> latency-bound, not BW-bound).

__global__ void k_agg1(const unsigned* __restrict__ g1, const int* __restrict__ row_start,
                       const int* __restrict__ deg, const int* __restrict__ col,
                       const float* __restrict__ dinv, const float* __restrict__ b1,
                       float* __restrict__ h2, int N) {
  int node = blockIdx.x * 4 + (threadIdx.x >> 6);
  if (node >= N) return;
  int lane = threadIdx.x & 63;
  unsigned su = g1[(size_t)node * 64 + lane];  // self-loop term
  float ax = unpack_lo(su), ay = unpack_hi(su);
  int start = row_start[node], cnt = deg[node];
  int j = 0;
  for (; j + 8 <= cnt; j += 8) {
    unsigned u[8];
#pragma unroll
    for (int t = 0; t < 8; ++t)
      u[t] = g1[(size_t)col[start + j + t] * 64 + lane];
#pragma unroll
    for (int t = 0; t < 8; ++t) {
      ax += unpack_lo(u[t]);
      ay += unpack_hi(u[t]);
    }
  }
  for (; j + 4 <= cnt; j += 4) {
    unsigned u[4];
#pragma unroll
    for (int t = 0; t < 4; ++t)
      u[t] = g1[(size_t)col[start + j + t] * 64 + lane];
#pragma unroll
    for (int t = 0; t < 4; ++t) {
      ax += unpack_lo(u[t]);
      ay += unpack_hi(u[t]);
    }
  }
  for (; j < cnt; ++j) {
    unsigned u = g1[(size_t)col[start + j] * 64 + lane];
    ax += unpack_lo(u);
    ay += unpack_hi(u);
  }
  float dn = dinv[node];
  float2 bb = ((const float2*)b1)[lane];
  float2 o;
  o.x = fmaxf(fmaf(ax, dn, bb.x), 0.f);
  o.y = fmaxf(fmaf(ay, dn, bb.y), 0.f);
  ((float2*)h2)[(size_t)node * 64 + lane] = o;
}

// ---------------- Aggregation 2: out = dinv[n]*(g2[n] + sum g2[nbr]) + b2, C=40 ----------------
// g2 packed bf16: 20 uints per row = 80 B. Lanes 0..19 active; unroll 8.

__global__ void k_agg2(const unsigned* __restrict__ g2, const int* __restrict__ row_start,
                       const int* __restrict__ deg, const int* __restrict__ col,
                       const float* __restrict__ dinv, const float* __restrict__ b2,
                       float* __restrict__ out, int N) {
  int node = blockIdx.x * 4 + (threadIdx.x >> 6);
  if (node >= N) return;
  int lane = threadIdx.x & 63;
  if (lane >= 20) return;
  unsigned su = g2[(size_t)node * 20 + lane];
  float ax = unpack_lo(su), ay = unpack_hi(su);
  int start = row_start[node], cnt = deg[node];
  int j = 0;
  for (; j + 8 <= cnt; j += 8) {
    unsigned u[8];
#pragma unroll
    for (int t = 0; t < 8; ++t)
      u[t] = g2[(size_t)col[start + j + t] * 20 + lane];
#pragma unroll
    for (int t = 0; t < 8; ++t) {
      ax += unpack_lo(u[t]);
      ay += unpack_hi(u[t]);
    }
  }
  for (; j < cnt; ++j) {
    unsigned u = g2[(size_t)col[start + j] * 20 + lane];
    ax += unpack_lo(u);
    ay += unpack_hi(u);
  }
  float dn = dinv[node];
  float2 o;
  o.x = fmaf(ax, dn, b2[2 * lane]);
  o.y = fmaf(ay, dn, b2[2 * lane + 1]);
  *(float2*)&out[(size_t)node * 40 + 2 * lane] = o;
}

// ---------------- launch ----------------

extern "C" void kernel_launch(void* const* d_in, const int* in_sizes, int n_in,
                              void* d_out, int out_size, void* d_ws, size_t ws_size,
                              hipStream_t stream) {
  const float* x = (const float*)d_in[0];
  const int* ei = (const int*)d_in[1];   // int64 in reference -> int32 on device
  const float* W1 = (const float*)d_in[2];
  const float* b1 = (const float*)d_in[3];
  const float* W2 = (const float*)d_in[4];
  const float* b2 = (const float*)d_in[5];

  const int F = in_sizes[3];       // 128
  const int N = in_sizes[0] / F;   // 100000
  const int E = in_sizes[1] / 2;   // 1600000
  const int* esrc = ei;
  const int* edst = ei + E;

  // workspace layout (bytes), offsets 256-aligned:
  //   deg:       0        .. 400384   (int[N])
  //   cursor:    400384   .. 400640   (int)
  //   fillcur:   400640   .. 801024   (int[N], init by k_alloc)
  //   dinv:      801024   .. 1201408  (float[N])
  //   row_start: 1201408  .. 1601792  (int[N])
  //   col:       1601792  .. 8001792  (int[E])
  //   g1/g2:     8002560  .. (bf16-packed, N*64 uints = 25.6 MB; g2 reuses)
  //   h2:        59202560 .. (fp32, N*128 = 51.2 MB)
  char* ws = (char*)d_ws;
  int* deg = (int*)(ws + 0);
  int* cursor = (int*)(ws + 400384);
  int* fillcur = (int*)(ws + 400640);
  float* dinv = (float*)(ws + 801024);
  int* row_start = (int*)(ws + 1201408);
  int* colx = (int*)(ws + 1601792);
  unsigned* g1 = (unsigned*)(ws + 8002560);
  float* h2 = (float*)(ws + 59202560);
  unsigned* g2 = g1;  // g1 is dead after k_agg1

  hipMemsetAsync(d_ws, 0, 400640, stream);  // zero deg + cursor

  k_count<<<2048, 256, 0, stream>>>(edst, E, deg);
  k_alloc<<<(N + 255) / 256, 256, 0, stream>>>(deg, N, dinv, row_start, fillcur, cursor);
  k_scatter<<<(E + 255) / 256, 256, 0, stream>>>(esrc, edst, E, fillcur, colx);

  // Layer 1: CT=32, RPT=4 -> RB=32, W in 2 phases of 64 k-rows. LDS 49.7KB.
  k_gemm_t<32, 4, 128, 64><<<3125, 256, 0, stream>>>(x, W1, dinv, g1, N);
  k_agg1<<<(N + 3) / 4, 256, 0, stream>>>(g1, row_start, deg, colx, dinv, b1, h2, N);
  // Layer 2: CT=16, RPT=2 -> RB=32, single W phase. LDS 37KB.
  k_gemm_t<16, 2, 40, 128><<<3125, 256, 0, stream>>>(h2, W2, dinv, g2, N);
  k_agg2<<<(N + 3) / 4, 256, 0, stream>>>(g2, row_start, deg, colx, dinv, b2,
                                          (float*)d_out, N);
}

// Round 8
// 366.755 us; speedup vs baseline: 1.4370x; 1.4370x over previous
//
#include <hip/hip_runtime.h>

// ---------------- bf16 pack/unpack (RNE) ----------------

__device__ inline unsigned pack_bf16(float a, float b) {
  unsigned ua = __float_as_uint(a), ub = __float_as_uint(b);
  ua += 0x7fffu + ((ua >> 16) & 1u);
  ub += 0x7fffu + ((ub >> 16) & 1u);
  return (ua >> 16) | (ub & 0xffff0000u);
}
__device__ inline float unpack_lo(unsigned u) { return __uint_as_float(u << 16); }
__device__ inline float unpack_hi(unsigned u) { return __uint_as_float(u & 0xffff0000u); }

// ---------------- Bucketed CSR build ----------------
// R7 evidence: global random 4B scatter/atomics cost a full 64B line each
// (WRITE_SIZE 107.8 MB = E*64B, ~810 GB/s random-line ceiling). Fix: bucket
// edges by 512-node dst ranges so all global writes are coalesced chunks or
// confined to one block's L2-resident slice.
// Buckets: b = dst >> 9, NB = ceil(N/512) = 196 (fits 256-slot LDS).
// Packed pair: u = src | (dst&511)<<17  (src < 2^17 for N=100000).

__global__ void kb_count(const int* __restrict__ dst, int E,
                         int* __restrict__ bucket_cnt, int NB) {
  __shared__ int h[256];
  h[threadIdx.x] = 0;
  __syncthreads();
  int i = blockIdx.x * blockDim.x + threadIdx.x;
  int stride = gridDim.x * blockDim.x;
  for (; i < E; i += stride) atomicAdd(&h[dst[i] >> 9], 1);
  __syncthreads();
  if (threadIdx.x < NB && h[threadIdx.x]) atomicAdd(&bucket_cnt[threadIdx.x], h[threadIdx.x]);
}

// single block, 256 threads: exclusive scan of bucket_cnt -> bucket_start/cursor
__global__ void kb_scan(const int* __restrict__ bucket_cnt, int NB, int E,
                        int* __restrict__ bucket_start, int* __restrict__ bucket_cursor) {
  int tid = threadIdx.x, lane = tid & 63, w = tid >> 6;
  int v = (tid < NB) ? bucket_cnt[tid] : 0;
  int x = v;
#pragma unroll
  for (int off = 1; off < 64; off <<= 1) {
    int u = __shfl_up(x, off);
    if (lane >= off) x += u;
  }
  __shared__ int ws4[4];
  if (lane == 63) ws4[w] = x;
  __syncthreads();
  int add = 0;
  for (int k = 0; k < w; ++k) add += ws4[k];
  x += add;
  int excl = x - v;
  if (tid < NB) {
    bucket_start[tid] = excl;
    bucket_cursor[tid] = excl;
  }
  if (tid == 0) bucket_start[NB] = E;
}

// tile-synchronous scatter: 4096 edges/block; per-tile LDS slot assignment,
// ONE global cursor atomic per (bin, tile); same-bucket writes contiguous.
__global__ __launch_bounds__(256) void kb_scatter(const int* __restrict__ src,
                                                  const int* __restrict__ dst, int E,
                                                  int* __restrict__ bucket_cursor,
                                                  unsigned* __restrict__ pairs) {
  constexpr int T = 16;
  __shared__ int bin_cnt[256], bin_base[256];
  bin_cnt[threadIdx.x] = 0;
  __syncthreads();
  int base = blockIdx.x * (256 * T);
  unsigned u[T];
  int bb[T], slot[T];
#pragma unroll
  for (int t = 0; t < T; ++t) {
    int e = base + t * 256 + threadIdx.x;
    if (e < E) {
      int s = src[e], d = dst[e];
      bb[t] = d >> 9;
      u[t] = (unsigned)s | ((unsigned)(d & 511) << 17);
      slot[t] = atomicAdd(&bin_cnt[bb[t]], 1);
    } else {
      bb[t] = -1;
    }
  }
  __syncthreads();
  if (bin_cnt[threadIdx.x] > 0)
    bin_base[threadIdx.x] = atomicAdd(&bucket_cursor[threadIdx.x], bin_cnt[threadIdx.x]);
  __syncthreads();
#pragma unroll
  for (int t = 0; t < T; ++t)
    if (bb[t] >= 0) pairs[bin_base[bb[t]] + slot[t]] = u[t];
}

// one block per bucket: LDS count -> scan -> deg/dinv/row_start (coalesced),
// then scatter col within the bucket's L2-resident slice.
__global__ __launch_bounds__(256) void kc_csr(const unsigned* __restrict__ pairs,
                                              const int* __restrict__ bucket_start,
                                              int N, float* __restrict__ dinv,
                                              int* __restrict__ row_start,
                                              int* __restrict__ deg,
                                              int* __restrict__ col) {
  int b = blockIdx.x;
  int pbase = bucket_start[b], m = bucket_start[b + 1] - pbase;
  int tid = threadIdx.x, lane = tid & 63, w = tid >> 6;
  __shared__ int cnt[512], cur[512];
  __shared__ int ws4[4];
  cnt[tid] = 0;
  cnt[tid + 256] = 0;
  __syncthreads();
  for (int i = tid; i < m; i += 256) atomicAdd(&cnt[pairs[pbase + i] >> 17], 1);
  __syncthreads();
  int c0 = cnt[2 * tid], c1 = cnt[2 * tid + 1];
  int p = c0 + c1, x = p;
#pragma unroll
  for (int off = 1; off < 64; off <<= 1) {
    int uu = __shfl_up(x, off);
    if (lane >= off) x += uu;
  }
  if (lane == 63) ws4[w] = x;
  __syncthreads();
  int add = 0;
  for (int k = 0; k < w; ++k) add += ws4[k];
  x += add;
  int xe = x - p;  // exclusive prefix of pair
  cur[2 * tid] = xe;
  cur[2 * tid + 1] = xe + c0;
  int n0 = b * 512 + 2 * tid;
  if (n0 < N) {
    deg[n0] = c0;
    dinv[n0] = rsqrtf((float)(c0 + 1));
    row_start[n0] = pbase + xe;
  }
  if (n0 + 1 < N) {
    deg[n0 + 1] = c1;
    dinv[n0 + 1] = rsqrtf((float)(c1 + 1));
    row_start[n0 + 1] = pbase + xe + c0;
  }
  __syncthreads();
  for (int i = tid; i < m; i += 256) {
    unsigned uu = pairs[pbase + i];
    int pos = atomicAdd(&cur[uu >> 17], 1);
    col[pbase + pos] = (int)(uu & 131071u);
  }
}

// ---------------- Tiled GEMM: G[r,c] = bf16(dinv[r] * sum_k X[r,k] * W[k,c]) ----------------
// Block 256. Thread = (cx, ry). Output packed bf16 (gather payload; fp32 acc).
// History: R3/R4 VGPR=256 + ~500MB scratch spill from unbounded k4 unroll;
// fixed by unroll 2 + launch_bounds(256,4) (128-VGPR cap). Xl pad +4 floats
// keeps b128 LDS reads conflict-free (R4: conflicts 3.2M -> 0).

template <int CT, int RPT, int NC, int KP>
__global__ __launch_bounds__(256, 4) void k_gemm_t(const float* __restrict__ X,
                                                   const float* __restrict__ W,
                                                   const float* __restrict__ dinv,
                                                   unsigned* __restrict__ G,  // packed bf16, NC/2 uints per row
                                                   int N) {
  constexpr int K = 128;
  constexpr int LDX = K + 4;
  constexpr int RT = 256 / CT;
  constexpr int RB = RT * RPT;
  constexpr int PHASES = K / KP;
  constexpr int KV = K / 4;

  __shared__ float Wl[KP * NC];
  __shared__ float Xl[RB * LDX];

  const int tid = threadIdx.x;
  const int row0 = blockIdx.x * RB;

  const float4* X4 = (const float4*)(X + (size_t)row0 * K);
  if (row0 + RB <= N) {
#pragma unroll
    for (int i = tid; i < RB * KV; i += 256) {
      int r = i / KV, c = i % KV;
      *(float4*)&Xl[r * LDX + c * 4] = X4[i];
    }
  } else {
    int lim = (N - row0) * KV;
    for (int i = tid; i < RB * KV; i += 256) {
      int r = i / KV, c = i % KV;
      *(float4*)&Xl[r * LDX + c * 4] =
          (i < lim) ? X4[i] : float4{0.f, 0.f, 0.f, 0.f};
    }
  }

  const int cx = tid % CT;
  const int ry = tid / CT;
  const int c0 = cx * 4;
  const bool cact = (c0 < NC);
  const int c0c = cact ? c0 : 0;

  float acc[RPT][4];
#pragma unroll
  for (int j = 0; j < RPT; ++j)
#pragma unroll
    for (int c = 0; c < 4; ++c) acc[j][c] = 0.f;

  for (int p = 0; p < PHASES; ++p) {
    constexpr int WV = KP * NC / 4;
    const float4* W4 = (const float4*)(W + (size_t)p * KP * NC);
    float4* Wl4 = (float4*)Wl;
    if (p > 0) __syncthreads();
#pragma unroll
    for (int i = tid; i < WV; i += 256) Wl4[i] = W4[i];
    __syncthreads();

#pragma unroll 2
    for (int k4 = 0; k4 < KP / 4; ++k4) {
      float4 xv[RPT], wv[4];
#pragma unroll
      for (int j = 0; j < RPT; ++j)
        xv[j] = *(const float4*)&Xl[(ry * RPT + j) * LDX + p * KP + k4 * 4];
#pragma unroll
      for (int kk = 0; kk < 4; ++kk)
        wv[kk] = *(const float4*)&Wl[(k4 * 4 + kk) * NC + c0c];
#pragma unroll
      for (int kk = 0; kk < 4; ++kk)
#pragma unroll
        for (int j = 0; j < RPT; ++j) {
          float xs = ((const float*)&xv[j])[kk];
#pragma unroll
          for (int c = 0; c < 4; ++c)
            acc[j][c] = fmaf(xs, ((const float*)&wv[kk])[c], acc[j][c]);
        }
    }
  }

  if (cact) {
#pragma unroll
    for (int j = 0; j < RPT; ++j) {
      int r = row0 + ry * RPT + j;
      if (r < N) {
        float d = dinv[r];
        uint2 o;
        o.x = pack_bf16(acc[j][0] * d, acc[j][1] * d);
        o.y = pack_bf16(acc[j][2] * d, acc[j][3] * d);
        *(uint2*)&G[(size_t)r * (NC / 2) + c0 / 2] = o;
      }
    }
  }
}

// ---------------- Aggregation 1: h2 = relu(dinv[n]*(g1[n] + sum g1[nbr]) + b1) ----------------
// g1 packed bf16: 64 uints (128 feats) per row = 256 B. One wave per node,
// one uint per lane; fp32 accumulate; unroll 8 for gather ILP.

__global__ void k_agg1(const unsigned* __restrict__ g1, const int* __restrict__ row_start,
                       const int* __restrict__ deg, const int* __restrict__ col,
                       const float* __restrict__ dinv, const float* __restrict__ b1,
                       float* __restrict__ h2, int N) {
  int node = blockIdx.x * 4 + (threadIdx.x >> 6);
  if (node >= N) return;
  int lane = threadIdx.x & 63;
  unsigned su = g1[(size_t)node * 64 + lane];  // self-loop term
  float ax = unpack_lo(su), ay = unpack_hi(su);
  int start = row_start[node], cnt = deg[node];
  int j = 0;
  for (; j + 8 <= cnt; j += 8) {
    unsigned u[8];
#pragma unroll
    for (int t = 0; t < 8; ++t)
      u[t] = g1[(size_t)col[start + j + t] * 64 + lane];
#pragma unroll
    for (int t = 0; t < 8; ++t) {
      ax += unpack_lo(u[t]);
      ay += unpack_hi(u[t]);
    }
  }
  for (; j + 4 <= cnt; j += 4) {
    unsigned u[4];
#pragma unroll
    for (int t = 0; t < 4; ++t)
      u[t] = g1[(size_t)col[start + j + t] * 64 + lane];
#pragma unroll
    for (int t = 0; t < 4; ++t) {
      ax += unpack_lo(u[t]);
      ay += unpack_hi(u[t]);
    }
  }
  for (; j < cnt; ++j) {
    unsigned u = g1[(size_t)col[start + j] * 64 + lane];
    ax += unpack_lo(u);
    ay += unpack_hi(u);
  }
  float dn = dinv[node];
  float2 bb = ((const float2*)b1)[lane];
  float2 o;
  o.x = fmaxf(fmaf(ax, dn, bb.x), 0.f);
  o.y = fmaxf(fmaf(ay, dn, bb.y), 0.f);
  ((float2*)h2)[(size_t)node * 64 + lane] = o;
}

// ---------------- Aggregation 2: out = dinv[n]*(g2[n] + sum g2[nbr]) + b2, C=40 ----------------
// g2 packed bf16: 20 uints per row = 80 B. Lanes 0..19 active; unroll 8.

__global__ void k_agg2(const unsigned* __restrict__ g2, const int* __restrict__ row_start,
                       const int* __restrict__ deg, const int* __restrict__ col,
                       const float* __restrict__ dinv, const float* __restrict__ b2,
                       float* __restrict__ out, int N) {
  int node = blockIdx.x * 4 + (threadIdx.x >> 6);
  if (node >= N) return;
  int lane = threadIdx.x & 63;
  if (lane >= 20) return;
  unsigned su = g2[(size_t)node * 20 + lane];
  float ax = unpack_lo(su), ay = unpack_hi(su);
  int start = row_start[node], cnt = deg[node];
  int j = 0;
  for (; j + 8 <= cnt; j += 8) {
    unsigned u[8];
#pragma unroll
    for (int t = 0; t < 8; ++t)
      u[t] = g2[(size_t)col[start + j + t] * 20 + lane];
#pragma unroll
    for (int t = 0; t < 8; ++t) {
      ax += unpack_lo(u[t]);
      ay += unpack_hi(u[t]);
    }
  }
  for (; j < cnt; ++j) {
    unsigned u = g2[(size_t)col[start + j] * 20 + lane];
    ax += unpack_lo(u);
    ay += unpack_hi(u);
  }
  float dn = dinv[node];
  float2 o;
  o.x = fmaf(ax, dn, b2[2 * lane]);
  o.y = fmaf(ay, dn, b2[2 * lane + 1]);
  *(float2*)&out[(size_t)node * 40 + 2 * lane] = o;
}

// ---------------- launch ----------------

extern "C" void kernel_launch(void* const* d_in, const int* in_sizes, int n_in,
                              void* d_out, int out_size, void* d_ws, size_t ws_size,
                              hipStream_t stream) {
  const float* x = (const float*)d_in[0];
  const int* ei = (const int*)d_in[1];   // int64 in reference -> int32 on device
  const float* W1 = (const float*)d_in[2];
  const float* b1 = (const float*)d_in[3];
  const float* W2 = (const float*)d_in[4];
  const float* b2 = (const float*)d_in[5];

  const int F = in_sizes[3];       // 128
  const int N = in_sizes[0] / F;   // 100000
  const int E = in_sizes[1] / 2;   // 1600000
  const int* esrc = ei;
  const int* edst = ei + E;
  const int NB = (N + 511) / 512;  // 196

  // workspace layout (bytes):
  //   bucket_cnt:    0        (1 KB)
  //   bucket_start:  4096     (NB+1 ints)
  //   bucket_cursor: 8192     (NB ints)
  //   dinv:          16384    (400 KB)
  //   row_start:     417792   (400 KB)
  //   deg:           819200   (400 KB)
  //   pairs:         1220608  (6.4 MB)
  //   col:           7621632  (6.4 MB)
  //   g1/g2:         14680064 (bf16-packed, 25.6 MB; g2 reuses)
  //   h2:            41943040 (fp32, 51.2 MB)
  char* ws = (char*)d_ws;
  int* bucket_cnt = (int*)(ws + 0);
  int* bucket_start = (int*)(ws + 4096);
  int* bucket_cursor = (int*)(ws + 8192);
  float* dinv = (float*)(ws + 16384);
  int* row_start = (int*)(ws + 417792);
  int* deg = (int*)(ws + 819200);
  unsigned* pairs = (unsigned*)(ws + 1220608);
  int* colx = (int*)(ws + 7621632);
  unsigned* g1 = (unsigned*)(ws + 14680064);
  float* h2 = (float*)(ws + 41943040);
  unsigned* g2 = g1;  // g1 is dead after k_agg1

  hipMemsetAsync(bucket_cnt, 0, 1024, stream);

  kb_count<<<256, 256, 0, stream>>>(edst, E, bucket_cnt, NB);
  kb_scan<<<1, 256, 0, stream>>>(bucket_cnt, NB, E, bucket_start, bucket_cursor);
  kb_scatter<<<(E + 4095) / 4096, 256, 0, stream>>>(esrc, edst, E, bucket_cursor, pairs);
  kc_csr<<<NB, 256, 0, stream>>>(pairs, bucket_start, N, dinv, row_start, deg, colx);

  // Layer 1: CT=32, RPT=4 -> RB=32, W in 2 phases of 64 k-rows. LDS 49.7KB.
  k_gemm_t<32, 4, 128, 64><<<3125, 256, 0, stream>>>(x, W1, dinv, g1, N);
  k_agg1<<<(N + 3) / 4, 256, 0, stream>>>(g1, row_start, deg, colx, dinv, b1, h2, N);
  // Layer 2: CT=16, RPT=2 -> RB=32, single W phase. LDS 37KB.
  k_gemm_t<16, 2, 40, 128><<<3125, 256, 0, stream>>>(h2, W2, dinv, g2, N);
  k_agg2<<<(N + 3) / 4, 256, 0, stream>>>(g2, row_start, deg, colx, dinv, b2,
                                          (float*)d_out, N);
}

// Round 9
// 326.487 us; speedup vs baseline: 1.6142x; 1.1233x over previous
//
#include <hip/hip_runtime.h>

typedef short s16x8 __attribute__((ext_vector_type(8)));
typedef float f32x4 __attribute__((ext_vector_type(4)));

// ---------------- bf16 pack/unpack (RNE) ----------------

__device__ inline unsigned pack_bf16(float a, float b) {
  unsigned ua = __float_as_uint(a), ub = __float_as_uint(b);
  ua += 0x7fffu + ((ua >> 16) & 1u);
  ub += 0x7fffu + ((ub >> 16) & 1u);
  return (ua >> 16) | (ub & 0xffff0000u);
}
__device__ inline float unpack_lo(unsigned u) { return __uint_as_float(u << 16); }
__device__ inline float unpack_hi(unsigned u) { return __uint_as_float(u & 0xffff0000u); }

// ---------------- Bucketed CSR build (R8: random-line writes -> coalesced; kept) ----------------

__global__ void kb_count(const int* __restrict__ dst, int E,
                         int* __restrict__ bucket_cnt, int NB) {
  __shared__ int h[256];
  h[threadIdx.x] = 0;
  __syncthreads();
  int i = blockIdx.x * blockDim.x + threadIdx.x;
  int stride = gridDim.x * blockDim.x;
  for (; i < E; i += stride) atomicAdd(&h[dst[i] >> 9], 1);
  __syncthreads();
  if (threadIdx.x < NB && h[threadIdx.x]) atomicAdd(&bucket_cnt[threadIdx.x], h[threadIdx.x]);
}

__global__ void kb_scan(const int* __restrict__ bucket_cnt, int NB, int E,
                        int* __restrict__ bucket_start, int* __restrict__ bucket_cursor) {
  int tid = threadIdx.x, lane = tid & 63, w = tid >> 6;
  int v = (tid < NB) ? bucket_cnt[tid] : 0;
  int x = v;
#pragma unroll
  for (int off = 1; off < 64; off <<= 1) {
    int u = __shfl_up(x, off);
    if (lane >= off) x += u;
  }
  __shared__ int ws4[4];
  if (lane == 63) ws4[w] = x;
  __syncthreads();
  int add = 0;
  for (int k = 0; k < w; ++k) add += ws4[k];
  x += add;
  int excl = x - v;
  if (tid < NB) {
    bucket_start[tid] = excl;
    bucket_cursor[tid] = excl;
  }
  if (tid == 0) bucket_start[NB] = E;
}

__global__ __launch_bounds__(256) void kb_scatter(const int* __restrict__ src,
                                                  const int* __restrict__ dst, int E,
                                                  int* __restrict__ bucket_cursor,
                                                  unsigned* __restrict__ pairs) {
  constexpr int T = 16;
  __shared__ int bin_cnt[256], bin_base[256];
  bin_cnt[threadIdx.x] = 0;
  __syncthreads();
  int base = blockIdx.x * (256 * T);
  unsigned u[T];
  int bb[T], slot[T];
#pragma unroll
  for (int t = 0; t < T; ++t) {
    int e = base + t * 256 + threadIdx.x;
    if (e < E) {
      int s = src[e], d = dst[e];
      bb[t] = d >> 9;
      u[t] = (unsigned)s | ((unsigned)(d & 511) << 17);
      slot[t] = atomicAdd(&bin_cnt[bb[t]], 1);
    } else {
      bb[t] = -1;
    }
  }
  __syncthreads();
  if (bin_cnt[threadIdx.x] > 0)
    bin_base[threadIdx.x] = atomicAdd(&bucket_cursor[threadIdx.x], bin_cnt[threadIdx.x]);
  __syncthreads();
#pragma unroll
  for (int t = 0; t < T; ++t)
    if (bb[t] >= 0) pairs[bin_base[bb[t]] + slot[t]] = u[t];
}

__global__ __launch_bounds__(256) void kc_csr(const unsigned* __restrict__ pairs,
                                              const int* __restrict__ bucket_start,
                                              int N, float* __restrict__ dinv,
                                              int* __restrict__ row_start,
                                              int* __restrict__ deg,
                                              int* __restrict__ col) {
  int b = blockIdx.x;
  int pbase = bucket_start[b], m = bucket_start[b + 1] - pbase;
  int tid = threadIdx.x, lane = tid & 63, w = tid >> 6;
  __shared__ int cnt[512], cur[512];
  __shared__ int ws4[4];
  cnt[tid] = 0;
  cnt[tid + 256] = 0;
  __syncthreads();
  for (int i = tid; i < m; i += 256) atomicAdd(&cnt[pairs[pbase + i] >> 17], 1);
  __syncthreads();
  int c0 = cnt[2 * tid], c1 = cnt[2 * tid + 1];
  int p = c0 + c1, x = p;
#pragma unroll
  for (int off = 1; off < 64; off <<= 1) {
    int uu = __shfl_up(x, off);
    if (lane >= off) x += uu;
  }
  if (lane == 63) ws4[w] = x;
  __syncthreads();
  int add = 0;
  for (int k = 0; k < w; ++k) add += ws4[k];
  x += add;
  int xe = x - p;
  cur[2 * tid] = xe;
  cur[2 * tid + 1] = xe + c0;
  int n0 = b * 512 + 2 * tid;
  if (n0 < N) {
    deg[n0] = c0;
    dinv[n0] = rsqrtf((float)(c0 + 1));
    row_start[n0] = pbase + xe;
  }
  if (n0 + 1 < N) {
    deg[n0 + 1] = c1;
    dinv[n0 + 1] = rsqrtf((float)(c1 + 1));
    row_start[n0 + 1] = pbase + xe + c0;
  }
  __syncthreads();
  for (int i = tid; i < m; i += 256) {
    unsigned uu = pairs[pbase + i];
    int pos = atomicAdd(&cur[uu >> 17], 1);
    col[pbase + pos] = (int)(uu & 131071u);
  }
}

// ---------------- W transpose + bf16 pack: WT[n][kd] = (bf16 W[2kd][n], bf16 W[2kd+1][n]) ----------------

__global__ void kw_trans(const float* __restrict__ W, int NC, int NT,
                         unsigned* __restrict__ WT) {
  int id = blockIdx.x * 256 + threadIdx.x;
  if (id >= NT * 64) return;
  int n = id >> 6, kd = id & 63;
  float a = 0.f, b = 0.f;
  if (n < NC) {
    a = W[(2 * kd) * NC + n];
    b = W[(2 * kd + 1) * NC + n];
  }
  WT[id] = pack_bf16(a, b);
}

// ---------------- MFMA GEMM: G[r,c] = bf16(dinv[r] * sum_k A[r,k]*W[k,c]) ----------------
// 16x16x32 bf16 MFMA, fp32 acc. Block 256 = 4 waves; block tile M=64 (16 rows
// per wave), full N per wave (NTILES n-tiles of 16). K=128 = 4 k-steps.
// Verified layouts (m89/m120): A[m=lane&15][k=quad*8+j]; B[k=quad*8+j][n=lane&15]
// (Ws holds W^T so B-frag reads are row-contiguous); D[n=lane&15][m=quad*4+reg].
// LDS rows padded to 136 bf16 (68 uints): b128 frag reads spread banks uniformly.
// R8 evidence for this rewrite: scalar path was LDS-port-bound (VALUBusy 50% =
// 768 port-cyc vs 384 SIMD-cyc per round); MFMA is 0.125 B/FLOP vs 2.0.

template <int NTILES, int GSTRIDE, int NCOLS, bool A_FP32>
__global__ __launch_bounds__(256, 4) void k_gemm_mfma(const void* __restrict__ Ain,
                                                      const unsigned* __restrict__ WT,
                                                      const float* __restrict__ dinv,
                                                      unsigned* __restrict__ G, int N) {
  __shared__ unsigned Ws[NTILES * 16 * 68];
  __shared__ unsigned As[64 * 68];

  const int tid = threadIdx.x;
  const int row0 = blockIdx.x * 64;

  // stage W^T (bf16-packed, linear in WT) into padded LDS rows
  constexpr int WV2 = NTILES * 16 * 32;  // uint2 count
  const uint2* WT2 = (const uint2*)WT;
#pragma unroll
  for (int i = tid; i < WV2; i += 256) {
    int r = i >> 5, kd2 = i & 31;
    *(uint2*)&Ws[r * 68 + kd2 * 2] = WT2[i];
  }

  // stage A tile: 64 rows x 128 k as bf16 into padded LDS rows
  if (A_FP32) {
    const float4* X4 = (const float4*)Ain + (size_t)row0 * 32;
#pragma unroll
    for (int i = tid; i < 2048; i += 256) {
      int r = i >> 5, c4 = i & 31;
      uint2 o = {0u, 0u};
      if (row0 + r < N) {
        float4 xv = X4[i];
        o.x = pack_bf16(xv.x, xv.y);
        o.y = pack_bf16(xv.z, xv.w);
      }
      *(uint2*)&As[r * 68 + c4 * 2] = o;
    }
  } else {
    const uint2* H2 = (const uint2*)Ain + (size_t)row0 * 32;
#pragma unroll
    for (int i = tid; i < 2048; i += 256) {
      int r = i >> 5, kd2 = i & 31;
      uint2 o = {0u, 0u};
      if (row0 + r < N) o = H2[i];
      *(uint2*)&As[r * 68 + kd2 * 2] = o;
    }
  }
  __syncthreads();

  const int w = tid >> 6, lane = tid & 63;
  const int quad = lane >> 4, n16 = lane & 15;

  f32x4 acc[NTILES];
#pragma unroll
  for (int t = 0; t < NTILES; ++t) acc[t] = {0.f, 0.f, 0.f, 0.f};

  const char* Ab = (const char*)As + (w * 16 + n16) * 272 + quad * 16;
  const char* Bb = (const char*)Ws + n16 * 272 + quad * 16;
#pragma unroll
  for (int s = 0; s < 4; ++s) {
    s16x8 a = *(const s16x8*)(Ab + s * 64);
#pragma unroll
    for (int t = 0; t < NTILES; ++t) {
      s16x8 b = *(const s16x8*)(Bb + t * 16 * 272 + s * 64);
      acc[t] = __builtin_amdgcn_mfma_f32_16x16x32_bf16(a, b, acc[t], 0, 0, 0);
    }
  }

  // epilogue: scale by dinv, pack col pairs via shfl_xor(1), even lanes store
#pragma unroll
  for (int reg = 0; reg < 4; ++reg) {
    int r = row0 + w * 16 + quad * 4 + reg;
    float dv = (r < N) ? dinv[r] : 0.f;
#pragma unroll
    for (int t = 0; t < NTILES; ++t) {
      float v = acc[t][reg] * dv;
      float vp = __shfl_xor(v, 1);
      int colc = t * 16 + n16;
      if ((n16 & 1) == 0 && colc < NCOLS && r < N)
        G[(size_t)r * GSTRIDE + t * 8 + (n16 >> 1)] = pack_bf16(v, vp);
    }
  }
}

// ---------------- Aggregation 1: h2 = bf16(relu(dinv[n]*(g1[n]+sum g1[nbr]) + b1)) ----------------
// g1 packed bf16: 64 uints/row. One wave/node, one uint/lane, fp32 acc.
// h2 now packed bf16 too (gemm2 is MFMA; halves write traffic).

__global__ void k_agg1(const unsigned* __restrict__ g1, const int* __restrict__ row_start,
                       const int* __restrict__ deg, const int* __restrict__ col,
                       const float* __restrict__ dinv, const float* __restrict__ b1,
                       unsigned* __restrict__ h2, int N) {
  int node = blockIdx.x * 4 + (threadIdx.x >> 6);
  if (node >= N) return;
  int lane = threadIdx.x & 63;
  unsigned su = g1[(size_t)node * 64 + lane];
  float ax = unpack_lo(su), ay = unpack_hi(su);
  int start = row_start[node], cnt = deg[node];
  int j = 0;
  for (; j + 8 <= cnt; j += 8) {
    unsigned u[8];
#pragma unroll
    for (int t = 0; t < 8; ++t)
      u[t] = g1[(size_t)col[start + j + t] * 64 + lane];
#pragma unroll
    for (int t = 0; t < 8; ++t) {
      ax += unpack_lo(u[t]);
      ay += unpack_hi(u[t]);
    }
  }
  for (; j + 4 <= cnt; j += 4) {
    unsigned u[4];
#pragma unroll
    for (int t = 0; t < 4; ++t)
      u[t] = g1[(size_t)col[start + j + t] * 64 + lane];
#pragma unroll
    for (int t = 0; t < 4; ++t) {
      ax += unpack_lo(u[t]);
      ay += unpack_hi(u[t]);
    }
  }
  for (; j < cnt; ++j) {
    unsigned u = g1[(size_t)col[start + j] * 64 + lane];
    ax += unpack_lo(u);
    ay += unpack_hi(u);
  }
  float dn = dinv[node];
  float2 bb = ((const float2*)b1)[lane];
  float ox = fmaxf(fmaf(ax, dn, bb.x), 0.f);
  float oy = fmaxf(fmaf(ay, dn, bb.y), 0.f);
  h2[(size_t)node * 64 + lane] = pack_bf16(ox, oy);
}

// ---------------- Aggregation 2: out = dinv[n]*(g2[n] + sum g2[nbr]) + b2, C=40 ----------------

__global__ void k_agg2(const unsigned* __restrict__ g2, const int* __restrict__ row_start,
                       const int* __restrict__ deg, const int* __restrict__ col,
                       const float* __restrict__ dinv, const float* __restrict__ b2,
                       float* __restrict__ out, int N) {
  int node = blockIdx.x * 4 + (threadIdx.x >> 6);
  if (node >= N) return;
  int lane = threadIdx.x & 63;
  if (lane >= 20) return;
  unsigned su = g2[(size_t)node * 20 + lane];
  float ax = unpack_lo(su), ay = unpack_hi(su);
  int start = row_start[node], cnt = deg[node];
  int j = 0;
  for (; j + 8 <= cnt; j += 8) {
    unsigned u[8];
#pragma unroll
    for (int t = 0; t < 8; ++t)
      u[t] = g2[(size_t)col[start + j + t] * 20 + lane];
#pragma unroll
    for (int t = 0; t < 8; ++t) {
      ax += unpack_lo(u[t]);
      ay += unpack_hi(u[t]);
    }
  }
  for (; j < cnt; ++j) {
    unsigned u = g2[(size_t)col[start + j] * 20 + lane];
    ax += unpack_lo(u);
    ay += unpack_hi(u);
  }
  float dn = dinv[node];
  float2 o;
  o.x = fmaf(ax, dn, b2[2 * lane]);
  o.y = fmaf(ay, dn, b2[2 * lane + 1]);
  *(float2*)&out[(size_t)node * 40 + 2 * lane] = o;
}

// ---------------- launch ----------------

extern "C" void kernel_launch(void* const* d_in, const int* in_sizes, int n_in,
                              void* d_out, int out_size, void* d_ws, size_t ws_size,
                              hipStream_t stream) {
  const float* x = (const float*)d_in[0];
  const int* ei = (const int*)d_in[1];   // int64 in reference -> int32 on device
  const float* W1 = (const float*)d_in[2];
  const float* b1 = (const float*)d_in[3];
  const float* W2 = (const float*)d_in[4];
  const float* b2 = (const float*)d_in[5];

  const int F = in_sizes[3];       // 128
  const int N = in_sizes[0] / F;   // 100000
  const int E = in_sizes[1] / 2;   // 1600000
  const int* esrc = ei;
  const int* edst = ei + E;
  const int NB = (N + 511) / 512;  // 196

  // workspace layout (bytes):
  //   bucket_cnt:    0        (1 KB)
  //   bucket_start:  4096
  //   bucket_cursor: 8192
  //   w1t:           16384    (32 KB: 128 n x 64 uints)
  //   w2t:           49152    (12.3 KB: 48 n x 64 uints)
  //   dinv:          65536    (400 KB)
  //   row_start:     466944   (400 KB)
  //   deg:           868352   (400 KB)
  //   pairs:         1269760  (6.4 MB)
  //   col:           7669760  (6.4 MB)
  //   g1/g2:         14073856 (bf16-packed, 25.6 MB; g2 reuses)
  //   h2:            39673856 (bf16-packed, 25.6 MB)
  char* ws = (char*)d_ws;
  int* bucket_cnt = (int*)(ws + 0);
  int* bucket_start = (int*)(ws + 4096);
  int* bucket_cursor = (int*)(ws + 8192);
  unsigned* w1t = (unsigned*)(ws + 16384);
  unsigned* w2t = (unsigned*)(ws + 49152);
  float* dinv = (float*)(ws + 65536);
  int* row_start = (int*)(ws + 466944);
  int* deg = (int*)(ws + 868352);
  unsigned* pairs = (unsigned*)(ws + 1269760);
  int* colx = (int*)(ws + 7669760);
  unsigned* g1 = (unsigned*)(ws + 14073856);
  unsigned* h2 = (unsigned*)(ws + 39673856);
  unsigned* g2 = g1;  // g1 is dead after k_agg1

  hipMemsetAsync(bucket_cnt, 0, 1024, stream);

  kb_count<<<256, 256, 0, stream>>>(edst, E, bucket_cnt, NB);
  kb_scan<<<1, 256, 0, stream>>>(bucket_cnt, NB, E, bucket_start, bucket_cursor);
  kb_scatter<<<(E + 4095) / 4096, 256, 0, stream>>>(esrc, edst, E, bucket_cursor, pairs);
  kc_csr<<<NB, 256, 0, stream>>>(pairs, bucket_start, N, dinv, row_start, deg, colx);

  kw_trans<<<32, 256, 0, stream>>>(W1, 128, 128, w1t);
  kw_trans<<<12, 256, 0, stream>>>(W2, 40, 48, w2t);

  const int gblocks = (N + 63) / 64;  // 1563
  // Layer 1: NTILES=8 (NC=128), A = x fp32. LDS 52.2 KB -> 3 blocks/CU.
  k_gemm_mfma<8, 64, 128, true><<<gblocks, 256, 0, stream>>>(x, w1t, dinv, g1, N);
  k_agg1<<<(N + 3) / 4, 256, 0, stream>>>(g1, row_start, deg, colx, dinv, b1, h2, N);
  // Layer 2: NTILES=3 (NC=40, padded 48), A = h2 bf16. LDS 30.5 KB.
  k_gemm_mfma<3, 20, 40, false><<<gblocks, 256, 0, stream>>>(h2, w2t, dinv, g2, N);
  k_agg2<<<(N + 3) / 4, 256, 0, stream>>>(g2, row_start, deg, colx, dinv, b2,
                                          (float*)d_out, N);
}

// Round 10
// 299.463 us; speedup vs baseline: 1.7599x; 1.0902x over previous
//
#include <hip/hip_runtime.h>

typedef short s16x8 __attribute__((ext_vector_type(8)));
typedef float f32x4 __attribute__((ext_vector_type(4)));

// ---------------- bf16 pack/unpack (RNE) ----------------

__device__ inline unsigned pack_bf16(float a, float b) {
  unsigned ua = __float_as_uint(a), ub = __float_as_uint(b);
  ua += 0x7fffu + ((ua >> 16) & 1u);
  ub += 0x7fffu + ((ub >> 16) & 1u);
  return (ua >> 16) | (ub & 0xffff0000u);
}
__device__ inline float unpack_lo(unsigned u) { return __uint_as_float(u << 16); }
__device__ inline float unpack_hi(unsigned u) { return __uint_as_float(u & 0xffff0000u); }

// ---------------- Bucketed CSR build (R8: random-line writes -> coalesced; kept) ----------------

__global__ void kb_count(const int* __restrict__ dst, int E,
                         int* __restrict__ bucket_cnt, int NB) {
  __shared__ int h[256];
  h[threadIdx.x] = 0;
  __syncthreads();
  int i = blockIdx.x * blockDim.x + threadIdx.x;
  int stride = gridDim.x * blockDim.x;
  for (; i < E; i += stride) atomicAdd(&h[dst[i] >> 9], 1);
  __syncthreads();
  if (threadIdx.x < NB && h[threadIdx.x]) atomicAdd(&bucket_cnt[threadIdx.x], h[threadIdx.x]);
}

__global__ void kb_scan(const int* __restrict__ bucket_cnt, int NB, int E,
                        int* __restrict__ bucket_start, int* __restrict__ bucket_cursor) {
  int tid = threadIdx.x, lane = tid & 63, w = tid >> 6;
  int v = (tid < NB) ? bucket_cnt[tid] : 0;
  int x = v;
#pragma unroll
  for (int off = 1; off < 64; off <<= 1) {
    int u = __shfl_up(x, off);
    if (lane >= off) x += u;
  }
  __shared__ int ws4[4];
  if (lane == 63) ws4[w] = x;
  __syncthreads();
  int add = 0;
  for (int k = 0; k < w; ++k) add += ws4[k];
  x += add;
  int excl = x - v;
  if (tid < NB) {
    bucket_start[tid] = excl;
    bucket_cursor[tid] = excl;
  }
  if (tid == 0) bucket_start[NB] = E;
}

__global__ __launch_bounds__(256) void kb_scatter(const int* __restrict__ src,
                                                  const int* __restrict__ dst, int E,
                                                  int* __restrict__ bucket_cursor,
                                                  unsigned* __restrict__ pairs) {
  constexpr int T = 16;
  __shared__ int bin_cnt[256], bin_base[256];
  bin_cnt[threadIdx.x] = 0;
  __syncthreads();
  int base = blockIdx.x * (256 * T);
  unsigned u[T];
  int bb[T], slot[T];
#pragma unroll
  for (int t = 0; t < T; ++t) {
    int e = base + t * 256 + threadIdx.x;
    if (e < E) {
      int s = src[e], d = dst[e];
      bb[t] = d >> 9;
      u[t] = (unsigned)s | ((unsigned)(d & 511) << 17);
      slot[t] = atomicAdd(&bin_cnt[bb[t]], 1);
    } else {
      bb[t] = -1;
    }
  }
  __syncthreads();
  if (bin_cnt[threadIdx.x] > 0)
    bin_base[threadIdx.x] = atomicAdd(&bucket_cursor[threadIdx.x], bin_cnt[threadIdx.x]);
  __syncthreads();
#pragma unroll
  for (int t = 0; t < T; ++t)
    if (bb[t] >= 0) pairs[bin_base[bb[t]] + slot[t]] = u[t];
}

__global__ __launch_bounds__(256) void kc_csr(const unsigned* __restrict__ pairs,
                                              const int* __restrict__ bucket_start,
                                              int N, float* __restrict__ dinv,
                                              int* __restrict__ row_start,
                                              int* __restrict__ deg,
                                              int* __restrict__ col) {
  int b = blockIdx.x;
  int pbase = bucket_start[b], m = bucket_start[b + 1] - pbase;
  int tid = threadIdx.x, lane = tid & 63, w = tid >> 6;
  __shared__ int cnt[512], cur[512];
  __shared__ int ws4[4];
  cnt[tid] = 0;
  cnt[tid + 256] = 0;
  __syncthreads();
  for (int i = tid; i < m; i += 256) atomicAdd(&cnt[pairs[pbase + i] >> 17], 1);
  __syncthreads();
  int c0 = cnt[2 * tid], c1 = cnt[2 * tid + 1];
  int p = c0 + c1, x = p;
#pragma unroll
  for (int off = 1; off < 64; off <<= 1) {
    int uu = __shfl_up(x, off);
    if (lane >= off) x += uu;
  }
  if (lane == 63) ws4[w] = x;
  __syncthreads();
  int add = 0;
  for (int k = 0; k < w; ++k) add += ws4[k];
  x += add;
  int xe = x - p;
  cur[2 * tid] = xe;
  cur[2 * tid + 1] = xe + c0;
  int n0 = b * 512 + 2 * tid;
  if (n0 < N) {
    deg[n0] = c0;
    dinv[n0] = rsqrtf((float)(c0 + 1));
    row_start[n0] = pbase + xe;
  }
  if (n0 + 1 < N) {
    deg[n0 + 1] = c1;
    dinv[n0 + 1] = rsqrtf((float)(c1 + 1));
    row_start[n0 + 1] = pbase + xe + c0;
  }
  __syncthreads();
  for (int i = tid; i < m; i += 256) {
    unsigned uu = pairs[pbase + i];
    int pos = atomicAdd(&cur[uu >> 17], 1);
    col[pbase + pos] = (int)(uu & 131071u);
  }
}

// ---------------- W transpose + bf16 pack: WT[n][kd] = (bf16 W[2kd][n], bf16 W[2kd+1][n]) ----------------

__global__ void kw_trans(const float* __restrict__ W, int NC, int NT,
                         unsigned* __restrict__ WT) {
  int id = blockIdx.x * 256 + threadIdx.x;
  if (id >= NT * 64) return;
  int n = id >> 6, kd = id & 63;
  float a = 0.f, b = 0.f;
  if (n < NC) {
    a = W[(2 * kd) * NC + n];
    b = W[(2 * kd + 1) * NC + n];
  }
  WT[id] = pack_bf16(a, b);
}

// ---------------- MFMA GEMM: G[r,c] = bf16(dinv[r] * sum_k A[r,k]*W[k,c]) ----------------
// 16x16x32 bf16 MFMA, fp32 acc. Block 256 = 4 waves; block tile M=64.
// Verified layouts (m89/m120): A[m=lane&15][k=quad*8+j]; B[k=quad*8+j][n=lane&15];
// D[n=lane&15][m=quad*4+reg]. LDS rows padded to 68 uints.

template <int NTILES, int GSTRIDE, int NCOLS, bool A_FP32>
__global__ __launch_bounds__(256, 4) void k_gemm_mfma(const void* __restrict__ Ain,
                                                      const unsigned* __restrict__ WT,
                                                      const float* __restrict__ dinv,
                                                      unsigned* __restrict__ G, int N) {
  __shared__ unsigned Ws[NTILES * 16 * 68];
  __shared__ unsigned As[64 * 68];

  const int tid = threadIdx.x;
  const int row0 = blockIdx.x * 64;

  constexpr int WV2 = NTILES * 16 * 32;  // uint2 count
  const uint2* WT2 = (const uint2*)WT;
#pragma unroll
  for (int i = tid; i < WV2; i += 256) {
    int r = i >> 5, kd2 = i & 31;
    *(uint2*)&Ws[r * 68 + kd2 * 2] = WT2[i];
  }

  if (A_FP32) {
    const float4* X4 = (const float4*)Ain + (size_t)row0 * 32;
#pragma unroll
    for (int i = tid; i < 2048; i += 256) {
      int r = i >> 5, c4 = i & 31;
      uint2 o = {0u, 0u};
      if (row0 + r < N) {
        float4 xv = X4[i];
        o.x = pack_bf16(xv.x, xv.y);
        o.y = pack_bf16(xv.z, xv.w);
      }
      *(uint2*)&As[r * 68 + c4 * 2] = o;
    }
  } else {
    const uint2* H2 = (const uint2*)Ain + (size_t)row0 * 32;
#pragma unroll
    for (int i = tid; i < 2048; i += 256) {
      int r = i >> 5, kd2 = i & 31;
      uint2 o = {0u, 0u};
      if (row0 + r < N) o = H2[i];
      *(uint2*)&As[r * 68 + kd2 * 2] = o;
    }
  }
  __syncthreads();

  const int w = tid >> 6, lane = tid & 63;
  const int quad = lane >> 4, n16 = lane & 15;

  f32x4 acc[NTILES];
#pragma unroll
  for (int t = 0; t < NTILES; ++t) acc[t] = {0.f, 0.f, 0.f, 0.f};

  const char* Ab = (const char*)As + (w * 16 + n16) * 272 + quad * 16;
  const char* Bb = (const char*)Ws + n16 * 272 + quad * 16;
#pragma unroll
  for (int s = 0; s < 4; ++s) {
    s16x8 a = *(const s16x8*)(Ab + s * 64);
#pragma unroll
    for (int t = 0; t < NTILES; ++t) {
      s16x8 b = *(const s16x8*)(Bb + t * 16 * 272 + s * 64);
      acc[t] = __builtin_amdgcn_mfma_f32_16x16x32_bf16(a, b, acc[t], 0, 0, 0);
    }
  }

#pragma unroll
  for (int reg = 0; reg < 4; ++reg) {
    int r = row0 + w * 16 + quad * 4 + reg;
    float dv = (r < N) ? dinv[r] : 0.f;
#pragma unroll
    for (int t = 0; t < NTILES; ++t) {
      float v = acc[t][reg] * dv;
      float vp = __shfl_xor(v, 1);
      int colc = t * 16 + n16;
      if ((n16 & 1) == 0 && colc < NCOLS && r < N)
        G[(size_t)r * GSTRIDE + t * 8 + (n16 >> 1)] = pack_bf16(v, vp);
    }
  }
}

// ---------------- Aggregation 1: h2 = bf16(relu(dinv[n]*(g1[n]+sum g1[nbr]) + b1)) ----------------
// g1 packed bf16: 64 uints/row. One wave/node, one uint/lane, fp32 acc.
// Unroll 16 for gather MLP (R9: agg kernels are latency-bound, not BW-bound).

__global__ void k_agg1(const unsigned* __restrict__ g1, const int* __restrict__ row_start,
                       const int* __restrict__ deg, const int* __restrict__ col,
                       const float* __restrict__ dinv, const float* __restrict__ b1,
                       unsigned* __restrict__ h2, int N) {
  int node = blockIdx.x * 4 + (threadIdx.x >> 6);
  if (node >= N) return;
  int lane = threadIdx.x & 63;
  unsigned su = g1[(size_t)node * 64 + lane];
  float ax = unpack_lo(su), ay = unpack_hi(su);
  int start = row_start[node], cnt = deg[node];
  int j = 0;
  for (; j + 16 <= cnt; j += 16) {
    unsigned u[16];
#pragma unroll
    for (int t = 0; t < 16; ++t)
      u[t] = g1[(size_t)col[start + j + t] * 64 + lane];
#pragma unroll
    for (int t = 0; t < 16; ++t) {
      ax += unpack_lo(u[t]);
      ay += unpack_hi(u[t]);
    }
  }
  for (; j + 8 <= cnt; j += 8) {
    unsigned u[8];
#pragma unroll
    for (int t = 0; t < 8; ++t)
      u[t] = g1[(size_t)col[start + j + t] * 64 + lane];
#pragma unroll
    for (int t = 0; t < 8; ++t) {
      ax += unpack_lo(u[t]);
      ay += unpack_hi(u[t]);
    }
  }
  for (; j + 4 <= cnt; j += 4) {
    unsigned u[4];
#pragma unroll
    for (int t = 0; t < 4; ++t)
      u[t] = g1[(size_t)col[start + j + t] * 64 + lane];
#pragma unroll
    for (int t = 0; t < 4; ++t) {
      ax += unpack_lo(u[t]);
      ay += unpack_hi(u[t]);
    }
  }
  for (; j < cnt; ++j) {
    unsigned u = g1[(size_t)col[start + j] * 64 + lane];
    ax += unpack_lo(u);
    ay += unpack_hi(u);
  }
  float dn = dinv[node];
  float2 bb = ((const float2*)b1)[lane];
  float ox = fmaxf(fmaf(ax, dn, bb.x), 0.f);
  float oy = fmaxf(fmaf(ay, dn, bb.y), 0.f);
  h2[(size_t)node * 64 + lane] = pack_bf16(ox, oy);
}

// ---------------- Aggregation 2: out = dinv[n]*(g2[n] + sum g2[nbr]) + b2, C=40 ----------------
// g2 packed bf16: 20 uints/row. R9 evidence: 20/64 active lanes -> issue-
// limited (1.4 TB/s, VALUBusy 25%). Now 3 nodes per wave (60/64 lanes):
// lane = sub*20 + f, 3x outstanding gathers per wave.

__global__ void k_agg2(const unsigned* __restrict__ g2, const int* __restrict__ row_start,
                       const int* __restrict__ deg, const int* __restrict__ col,
                       const float* __restrict__ dinv, const float* __restrict__ b2,
                       float* __restrict__ out, int N) {
  int lane = threadIdx.x & 63;
  int sub = lane / 20;            // 0..2 active, 3 idle
  int f = lane - sub * 20;        // 0..19
  int node = (blockIdx.x * 4 + (threadIdx.x >> 6)) * 3 + sub;
  if (sub >= 3 || node >= N) return;
  unsigned su = g2[(size_t)node * 20 + f];
  float ax = unpack_lo(su), ay = unpack_hi(su);
  int start = row_start[node], cnt = deg[node];
  int j = 0;
  for (; j + 8 <= cnt; j += 8) {
    unsigned u[8];
#pragma unroll
    for (int t = 0; t < 8; ++t)
      u[t] = g2[(size_t)col[start + j + t] * 20 + f];
#pragma unroll
    for (int t = 0; t < 8; ++t) {
      ax += unpack_lo(u[t]);
      ay += unpack_hi(u[t]);
    }
  }
  for (; j + 4 <= cnt; j += 4) {
    unsigned u[4];
#pragma unroll
    for (int t = 0; t < 4; ++t)
      u[t] = g2[(size_t)col[start + j + t] * 20 + f];
#pragma unroll
    for (int t = 0; t < 4; ++t) {
      ax += unpack_lo(u[t]);
      ay += unpack_hi(u[t]);
    }
  }
  for (; j < cnt; ++j) {
    unsigned u = g2[(size_t)col[start + j] * 20 + f];
    ax += unpack_lo(u);
    ay += unpack_hi(u);
  }
  float dn = dinv[node];
  float2 o;
  o.x = fmaf(ax, dn, b2[2 * f]);
  o.y = fmaf(ay, dn, b2[2 * f + 1]);
  *(float2*)&out[(size_t)node * 40 + 2 * f] = o;
}

// ---------------- launch ----------------

extern "C" void kernel_launch(void* const* d_in, const int* in_sizes, int n_in,
                              void* d_out, int out_size, void* d_ws, size_t ws_size,
                              hipStream_t stream) {
  const float* x = (const float*)d_in[0];
  const int* ei = (const int*)d_in[1];   // int64 in reference -> int32 on device
  const float* W1 = (const float*)d_in[2];
  const float* b1 = (const float*)d_in[3];
  const float* W2 = (const float*)d_in[4];
  const float* b2 = (const float*)d_in[5];

  const int F = in_sizes[3];       // 128
  const int N = in_sizes[0] / F;   // 100000
  const int E = in_sizes[1] / 2;   // 1600000
  const int* esrc = ei;
  const int* edst = ei + E;
  const int NB = (N + 511) / 512;  // 196

  // workspace layout (bytes):
  char* ws = (char*)d_ws;
  int* bucket_cnt = (int*)(ws + 0);
  int* bucket_start = (int*)(ws + 4096);
  int* bucket_cursor = (int*)(ws + 8192);
  unsigned* w1t = (unsigned*)(ws + 16384);
  unsigned* w2t = (unsigned*)(ws + 49152);
  float* dinv = (float*)(ws + 65536);
  int* row_start = (int*)(ws + 466944);
  int* deg = (int*)(ws + 868352);
  unsigned* pairs = (unsigned*)(ws + 1269760);
  int* colx = (int*)(ws + 7669760);
  unsigned* g1 = (unsigned*)(ws + 14073856);
  unsigned* h2 = (unsigned*)(ws + 39673856);
  unsigned* g2 = g1;  // g1 is dead after k_agg1

  hipMemsetAsync(bucket_cnt, 0, 1024, stream);

  kb_count<<<256, 256, 0, stream>>>(edst, E, bucket_cnt, NB);
  kb_scan<<<1, 256, 0, stream>>>(bucket_cnt, NB, E, bucket_start, bucket_cursor);
  kb_scatter<<<(E + 4095) / 4096, 256, 0, stream>>>(esrc, edst, E, bucket_cursor, pairs);
  kc_csr<<<NB, 256, 0, stream>>>(pairs, bucket_start, N, dinv, row_start, deg, colx);

  kw_trans<<<32, 256, 0, stream>>>(W1, 128, 128, w1t);
  kw_trans<<<12, 256, 0, stream>>>(W2, 40, 48, w2t);

  const int gblocks = (N + 63) / 64;  // 1563
  // Layer 1: NTILES=8 (NC=128), A = x fp32. LDS 52.2 KB -> 3 blocks/CU.
  k_gemm_mfma<8, 64, 128, true><<<gblocks, 256, 0, stream>>>(x, w1t, dinv, g1, N);
  k_agg1<<<(N + 3) / 4, 256, 0, stream>>>(g1, row_start, deg, colx, dinv, b1, h2, N);
  // Layer 2: NTILES=3 (NC=40, padded 48), A = h2 bf16. LDS 30.5 KB.
  k_gemm_mfma<3, 20, 40, false><<<gblocks, 256, 0, stream>>>(h2, w2t, dinv, g2, N);
  // agg2: 12 nodes per block (4 waves x 3 nodes).
  k_agg2<<<(N + 11) / 12, 256, 0, stream>>>(g2, row_start, deg, colx, dinv, b2,
                                            (float*)d_out, N);
}